// Round 2
// baseline (317.040 us; speedup 1.0000x reference)
//
#include <hip/hip_runtime.h>

typedef unsigned short u16;
typedef __bf16 bf16x8 __attribute__((ext_vector_type(8)));
typedef float f32x4 __attribute__((ext_vector_type(4)));

#define LOG2E 1.4426950408889634f
#define EXP2(x) __builtin_amdgcn_exp2f(x)

__device__ __forceinline__ u16 f2bf(float f) {
  unsigned int u = __float_as_uint(f);
  u += 0x7fffu + ((u >> 16) & 1u);
  return (u16)(u >> 16);
}

// async global->LDS, 16B per lane. LDS dest must be wave-uniform base + lane*16.
__device__ __forceinline__ void gld16(u16* lds, const u16* g) {
  __builtin_amdgcn_global_load_lds((const __attribute__((address_space(1))) unsigned int*)g,
                                   (__attribute__((address_space(3))) unsigned int*)lds,
                                   16, 0, 0);
}

__device__ __forceinline__ bf16x8 ldsv(const u16* p) {
  return *(const bf16x8*)p;
}

// ---------------- prep: fp32 -> bf16 conversions ----------------
// segments in float4-quads: x 1048576 | Wq 262144 | Wk 262144 | Wv 262144 | Wo 262144
__global__ __launch_bounds__(256) void k_prep(const float* __restrict__ x,
    const float* __restrict__ wq, const float* __restrict__ wk,
    const float* __restrict__ wv, const float* __restrict__ wo,
    u16* __restrict__ xb, u16* __restrict__ wqkvb, u16* __restrict__ wob) {
  unsigned gid = blockIdx.x * 256u + threadIdx.x;
  const float4* src;
  u16* dst;
  unsigned off;
  if (gid < 1048576u)      { src = (const float4*)x;  dst = xb;              off = gid; }
  else if (gid < 1310720u) { src = (const float4*)wq; dst = wqkvb;           off = gid - 1048576u; }
  else if (gid < 1572864u) { src = (const float4*)wk; dst = wqkvb + 1048576; off = gid - 1310720u; }
  else if (gid < 1835008u) { src = (const float4*)wv; dst = wqkvb + 2097152; off = gid - 1572864u; }
  else                     { src = (const float4*)wo; dst = wob;             off = gid - 1835008u; }
  float4 f = src[off];
  ushort4 o;
  o.x = f2bf(f.x); o.y = f2bf(f.y); o.z = f2bf(f.z); o.w = f2bf(f.w);
  ((ushort4*)dst)[off] = o;
}

// rope tables: cos/sin of l * theta^(-i/32), [2048][32] fp32 (matches reference fp32 math)
__global__ __launch_bounds__(256) void k_rope(float* __restrict__ cosT, float* __restrict__ sinT) {
  int t = blockIdx.x * 256 + threadIdx.x;  // 65536
  int l = t >> 5, i = t & 31;
  float inv = powf(10000.0f, -(float)i * (1.0f / 32.0f));
  float ang = (float)l * inv;
  float s, c;
  sincosf(ang, &s, &c);
  cosT[t] = c;
  sinT[t] = s;
}

// ---------------- shared GEMM main loop (m97 structure) ----------------
// C[m][n] = sum_k A[m][k]*B[n][k]; A,B row-major with ld=1024, K=1024.
// 128x128 block tile, 4 waves in 2x2, each wave 64x64 = 4x4 MFMA tiles.
__device__ __forceinline__ void gemm_loop(const u16* __restrict__ A, const u16* __restrict__ B,
                                          int m0, int n0, u16* As, u16* Bs, f32x4 acc[4][4]) {
  const int tid = threadIdx.x;
  const int lane = tid & 63, wave = tid >> 6;
  const int quad = lane >> 4, l16 = lane & 15;
  const int wm = wave & 1, wn = wave >> 1;

#pragma unroll
  for (int i = 0; i < 4; ++i)
#pragma unroll
    for (int j = 0; j < 4; ++j)
      acc[i][j] = (f32x4){0.f, 0.f, 0.f, 0.f};

  for (int kt = 0; kt < 16; ++kt) {
    int kb = kt * 64;
#pragma unroll
    for (int it = 0; it < 4; ++it) {
      int idx = it * 256 + tid;       // 0..1023 chunk id
      int row = idx >> 3, c8 = idx & 7;
      gld16(As + idx * 8, A + (long)(m0 + row) * 1024 + kb + c8 * 8);
      gld16(Bs + idx * 8, B + (long)(n0 + row) * 1024 + kb + c8 * 8);
    }
    __syncthreads();
#pragma unroll
    for (int kk = 0; kk < 2; ++kk) {
      bf16x8 a[4], b[4];
#pragma unroll
      for (int i = 0; i < 4; ++i)
        a[i] = ldsv(As + (wm * 64 + i * 16 + l16) * 64 + kk * 32 + quad * 8);
#pragma unroll
      for (int j = 0; j < 4; ++j)
        b[j] = ldsv(Bs + (wn * 64 + j * 16 + l16) * 64 + kk * 32 + quad * 8);
#pragma unroll
      for (int i = 0; i < 4; ++i)
#pragma unroll
        for (int j = 0; j < 4; ++j)
          acc[i][j] = __builtin_amdgcn_mfma_f32_16x16x32_bf16(a[i], b[j], acc[i][j], 0, 0, 0);
    }
    __syncthreads();
  }
}

// ---------------- QKV projection + bias + RoPE + scatter ----------------
__global__ __launch_bounds__(256) void k_qkv(const u16* __restrict__ xb, const u16* __restrict__ wqkvb,
    const float* __restrict__ bq, const float* __restrict__ bk, const float* __restrict__ bv,
    const float* __restrict__ cosT, const float* __restrict__ sinT,
    u16* __restrict__ Qg, u16* __restrict__ Kg, u16* __restrict__ VTg) {
  __shared__ __align__(16) u16 As[128 * 64];
  __shared__ __align__(16) u16 Bs[128 * 64];
  f32x4 acc[4][4];
  int m0 = blockIdx.y * 128, n0 = blockIdx.x * 128;
  gemm_loop(xb, wqkvb, m0, n0, As, Bs, acc);

  const int tid = threadIdx.x, lane = tid & 63, wave = tid >> 6;
  const int quad = lane >> 4, l16 = lane & 15;
  const int wm = wave & 1, wn = wave >> 1;

#pragma unroll
  for (int j = 0; j < 4; ++j) {
    int n = n0 + wn * 64 + j * 16 + l16;   // 0..3071
    int qsel = n >> 10;                    // 0=q 1=k 2=v (uniform across wave)
    int fcol = n & 1023;
    int h = fcol >> 6, d = fcol & 63;
    float bias = (qsel == 0) ? bq[fcol] : (qsel == 1) ? bk[fcol] : bv[fcol];
    int pi = d >> 1;
    float sgn = (d & 1) ? 1.0f : -1.0f;    // even d: -x_{d+1}; odd d: +x_{d-1}
#pragma unroll
    for (int i = 0; i < 4; ++i) {
#pragma unroll
      for (int r = 0; r < 4; ++r) {
        int m = m0 + wm * 64 + i * 16 + quad * 4 + r;  // token
        int bidx = m >> 11, l = m & 2047;
        float v = acc[i][j][r] + bias;
        float partner = __shfl_xor(v, 1);  // value at d^1 (adjacent lane), bias included
        if (qsel == 2) {
          // V stored transposed: [BH][64][2048]
          VTg[(((long)bidx * 16 + h) * 64 + d) * 2048 + l] = f2bf(v);
        } else {
          float c = cosT[l * 32 + pi], s = sinT[l * 32 + pi];
          float o = v * c + sgn * partner * s;
          if (qsel == 0) {
            o *= 0.125f;  // fold 1/sqrt(HD), exact in bf16
            Qg[(((long)bidx * 16 + h) * 2048 + l) * 64 + d] = f2bf(o);
          } else {
            Kg[(((long)bidx * 16 + h) * 2048 + l) * 64 + d] = f2bf(o);
          }
        }
      }
    }
  }
}

// ---------------- flash attention ----------------
// grid (16 q-tiles, 32 bh), 256 thr. Q-tile 128 rows; wave owns 32 rows (2 row-tiles).
__global__ __launch_bounds__(256, 2) void k_attn(const u16* __restrict__ Qg, const u16* __restrict__ Kg,
    const u16* __restrict__ VTg, u16* __restrict__ Ctx) {
  __shared__ __align__(16) u16 Ks[128 * 64];   // 16 KB
  __shared__ __align__(16) u16 Vs[64 * 128];   // 16 KB (V^T tile: [d][s])
  __shared__ __align__(16) u16 Ps[128 * 128];  // 32 KB
  const int tid = threadIdx.x, lane = tid & 63, wave = tid >> 6;
  const int quad = lane >> 4, l16 = lane & 15;
  const int bh = blockIdx.y;
  const int m0 = blockIdx.x * 128;
  const u16* Qb = Qg + (long)bh * 2048 * 64;
  const u16* Kb = Kg + (long)bh * 2048 * 64;
  const u16* Vb = VTg + (long)bh * 64 * 2048;

  // Q fragments in registers (A-operand layout), rows wave*32 + rt*16 + l16
  bf16x8 qf[2][2];
#pragma unroll
  for (int rt = 0; rt < 2; ++rt)
#pragma unroll
    for (int kk = 0; kk < 2; ++kk)
      qf[rt][kk] = *(const bf16x8*)(Qb + (long)(m0 + wave * 32 + rt * 16 + l16) * 64 + kk * 32 + quad * 8);

  float M[2][4], Ls[2][4];
  f32x4 oacc[2][4];
#pragma unroll
  for (int rt = 0; rt < 2; ++rt) {
#pragma unroll
    for (int r = 0; r < 4; ++r) { M[rt][r] = -3.0e38f; Ls[rt][r] = 0.f; }
#pragma unroll
    for (int dt = 0; dt < 4; ++dt) oacc[rt][dt] = (f32x4){0.f, 0.f, 0.f, 0.f};
  }

  for (int st = 0; st < 16; ++st) {
    int s0 = st * 128;
    // stage K tile [128][64] and V^T tile [64][128]
#pragma unroll
    for (int it = 0; it < 4; ++it) {
      int idx = it * 256 + tid;
      { int row = idx >> 3, c8 = idx & 7;
        gld16(Ks + idx * 8, Kb + (long)(s0 + row) * 64 + c8 * 8); }
      { int row = idx >> 4, c8 = idx & 15;
        gld16(Vs + idx * 8, Vb + (long)row * 2048 + s0 + c8 * 8); }
    }
    __syncthreads();

    // scores S[m][s], wave rows = wave*32 + rt*16, all 128 cols
    f32x4 sacc[2][8];
#pragma unroll
    for (int rt = 0; rt < 2; ++rt)
#pragma unroll
      for (int ct = 0; ct < 8; ++ct)
        sacc[rt][ct] = (f32x4){0.f, 0.f, 0.f, 0.f};
#pragma unroll
    for (int kk = 0; kk < 2; ++kk) {
      bf16x8 bfr[8];
#pragma unroll
      for (int ct = 0; ct < 8; ++ct)
        bfr[ct] = ldsv(Ks + (ct * 16 + l16) * 64 + kk * 32 + quad * 8);
#pragma unroll
      for (int rt = 0; rt < 2; ++rt)
#pragma unroll
        for (int ct = 0; ct < 8; ++ct)
          sacc[rt][ct] = __builtin_amdgcn_mfma_f32_16x16x32_bf16(qf[rt][kk], bfr[ct], sacc[rt][ct], 0, 0, 0);
    }

    // online softmax (row stats per (quad,r) via 16-lane shfl reductions)
#pragma unroll
    for (int rt = 0; rt < 2; ++rt) {
      float mx[4], rs[4], alpha[4];
#pragma unroll
      for (int r = 0; r < 4; ++r) {
        float m_ = sacc[rt][0][r];
#pragma unroll
        for (int ct = 1; ct < 8; ++ct) m_ = fmaxf(m_, sacc[rt][ct][r]);
#pragma unroll
        for (int msk = 1; msk < 16; msk <<= 1) m_ = fmaxf(m_, __shfl_xor(m_, msk));
        float mnew = fmaxf(M[rt][r], m_);
        alpha[r] = EXP2((M[rt][r] - mnew) * LOG2E);
        M[rt][r] = mnew;
        mx[r] = mnew;
        rs[r] = 0.f;
      }
#pragma unroll
      for (int ct = 0; ct < 8; ++ct) {
#pragma unroll
        for (int r = 0; r < 4; ++r) {
          float p = EXP2((sacc[rt][ct][r] - mx[r]) * LOG2E);
          rs[r] += p;
          Ps[(wave * 32 + rt * 16 + quad * 4 + r) * 128 + ct * 16 + l16] = f2bf(p);
        }
      }
#pragma unroll
      for (int r = 0; r < 4; ++r) {
        float s_ = rs[r];
#pragma unroll
        for (int msk = 1; msk < 16; msk <<= 1) s_ += __shfl_xor(s_, msk);
        Ls[rt][r] = Ls[rt][r] * alpha[r] + s_;
      }
#pragma unroll
      for (int dt = 0; dt < 4; ++dt)
#pragma unroll
        for (int r = 0; r < 4; ++r)
          oacc[rt][dt][r] *= alpha[r];
    }
    __syncthreads();

    // O += P @ V  (A = P rows of own wave, B = V^T rows = d)
#pragma unroll
    for (int ks = 0; ks < 4; ++ks) {
      bf16x8 pa0 = ldsv(Ps + (wave * 32 + 0 * 16 + l16) * 128 + ks * 32 + quad * 8);
      bf16x8 pa1 = ldsv(Ps + (wave * 32 + 1 * 16 + l16) * 128 + ks * 32 + quad * 8);
#pragma unroll
      for (int dt = 0; dt < 4; ++dt) {
        bf16x8 vb = ldsv(Vs + (dt * 16 + l16) * 128 + ks * 32 + quad * 8);
        oacc[0][dt] = __builtin_amdgcn_mfma_f32_16x16x32_bf16(pa0, vb, oacc[0][dt], 0, 0, 0);
        oacc[1][dt] = __builtin_amdgcn_mfma_f32_16x16x32_bf16(pa1, vb, oacc[1][dt], 0, 0, 0);
      }
    }
    __syncthreads();
  }

  // finalize: divide by l, store context token-major [4096][1024] bf16
  const int b = bh >> 4, h = bh & 15;
#pragma unroll
  for (int rt = 0; rt < 2; ++rt) {
#pragma unroll
    for (int dt = 0; dt < 4; ++dt) {
#pragma unroll
      for (int r = 0; r < 4; ++r) {
        float o = oacc[rt][dt][r] / Ls[rt][r];
        int l = m0 + wave * 32 + rt * 16 + quad * 4 + r;
        Ctx[((long)(b * 2048 + l)) * 1024 + h * 64 + dt * 16 + l16] = f2bf(o);
      }
    }
  }
}

// ---------------- output projection ----------------
__global__ __launch_bounds__(256) void k_out(const u16* __restrict__ Ctx, const u16* __restrict__ wob,
    const float* __restrict__ bo, float* __restrict__ out) {
  __shared__ __align__(16) u16 As[128 * 64];
  __shared__ __align__(16) u16 Bs[128 * 64];
  f32x4 acc[4][4];
  int m0 = blockIdx.y * 128, n0 = blockIdx.x * 128;
  gemm_loop(Ctx, wob, m0, n0, As, Bs, acc);
  const int tid = threadIdx.x, lane = tid & 63, wave = tid >> 6;
  const int quad = lane >> 4, l16 = lane & 15;
  const int wm = wave & 1, wn = wave >> 1;
#pragma unroll
  for (int i = 0; i < 4; ++i)
#pragma unroll
    for (int j = 0; j < 4; ++j) {
      int n = n0 + wn * 64 + j * 16 + l16;
      float b_ = bo[n];
#pragma unroll
      for (int r = 0; r < 4; ++r) {
        int m = m0 + wm * 64 + i * 16 + quad * 4 + r;
        out[(long)m * 1024 + n] = acc[i][j][r] + b_;
      }
    }
}

extern "C" void kernel_launch(void* const* d_in, const int* in_sizes, int n_in,
                              void* d_out, int out_size, void* d_ws, size_t ws_size,
                              hipStream_t stream) {
  const float* x  = (const float*)d_in[0];
  const float* Wq = (const float*)d_in[1];
  const float* bq = (const float*)d_in[2];
  const float* Wk = (const float*)d_in[3];
  const float* bk = (const float*)d_in[4];
  const float* Wv = (const float*)d_in[5];
  const float* bv = (const float*)d_in[6];
  const float* Wo = (const float*)d_in[7];
  const float* bo = (const float*)d_in[8];
  float* out = (float*)d_out;

  char* ws = (char*)d_ws;
  u16* xb    = (u16*)(ws);                       // 8 MB  [4096][1024] bf16
  u16* wqkvb = (u16*)(ws + (8ul << 20));         // 6 MB  [3072][1024] bf16
  u16* wob   = (u16*)(ws + (14ul << 20));        // 2 MB  [1024][1024] bf16
  u16* Qg    = (u16*)(ws + (16ul << 20));        // 8 MB  [32][2048][64] bf16 (pre-scaled)
  u16* Kg    = (u16*)(ws + (24ul << 20));        // 8 MB  [32][2048][64] bf16
  u16* VTg   = (u16*)(ws + (32ul << 20));        // 8 MB  [32][64][2048] bf16
  u16* Ctx   = (u16*)(ws + (40ul << 20));        // 8 MB  [4096][1024] bf16
  float* cosT = (float*)(ws + (48ul << 20));     // 256 KB [2048][32]
  float* sinT = (float*)(ws + (48ul << 20) + (256ul << 10));

  k_prep<<<dim3(8192), dim3(256), 0, stream>>>(x, Wq, Wk, Wv, Wo, xb, wqkvb, wob);
  k_rope<<<dim3(256), dim3(256), 0, stream>>>(cosT, sinT);
  k_qkv<<<dim3(24, 32), dim3(256), 0, stream>>>(xb, wqkvb, bq, bk, bv, cosT, sinT, Qg, Kg, VTg);
  k_attn<<<dim3(16, 32), dim3(256), 0, stream>>>(Qg, Kg, VTg, Ctx);
  k_out<<<dim3(8, 32), dim3(256), 0, stream>>>(Ctx, wob, bo, out);
}

// Round 3
// 242.527 us; speedup vs baseline: 1.3072x; 1.3072x over previous
//
#include <hip/hip_runtime.h>

typedef unsigned short u16;
typedef __bf16 bf16x8 __attribute__((ext_vector_type(8)));
typedef float f32x4 __attribute__((ext_vector_type(4)));

#define LOG2E 1.4426950408889634f
#define EXP2(x) __builtin_amdgcn_exp2f(x)
// fixed softmax shift: p = exp(S - 11) == exp2(S*LOG2E - 11*LOG2E)
#define NFM (-11.0f * LOG2E)

__device__ __forceinline__ u16 f2bf(float f) {
  unsigned int u = __float_as_uint(f);
  u += 0x7fffu + ((u >> 16) & 1u);
  return (u16)(u >> 16);
}

// async global->LDS, 16B per lane. LDS dest must be wave-uniform base + lane*16.
__device__ __forceinline__ void gld16(u16* lds, const u16* g) {
  __builtin_amdgcn_global_load_lds((const __attribute__((address_space(1))) unsigned int*)g,
                                   (__attribute__((address_space(3))) unsigned int*)lds,
                                   16, 0, 0);
}

__device__ __forceinline__ bf16x8 ldsv(const u16* p) {
  return *(const bf16x8*)p;
}

union U8 { uint4 u; bf16x8 v; };

// ---------------- prep: fp32 -> bf16 conversions ----------------
__global__ __launch_bounds__(256) void k_prep(const float* __restrict__ x,
    const float* __restrict__ wq, const float* __restrict__ wk,
    const float* __restrict__ wv, const float* __restrict__ wo,
    u16* __restrict__ xb, u16* __restrict__ wqkvb, u16* __restrict__ wob) {
  unsigned gid = blockIdx.x * 256u + threadIdx.x;
  const float4* src;
  u16* dst;
  unsigned off;
  if (gid < 1048576u)      { src = (const float4*)x;  dst = xb;              off = gid; }
  else if (gid < 1310720u) { src = (const float4*)wq; dst = wqkvb;           off = gid - 1048576u; }
  else if (gid < 1572864u) { src = (const float4*)wk; dst = wqkvb + 1048576; off = gid - 1310720u; }
  else if (gid < 1835008u) { src = (const float4*)wv; dst = wqkvb + 2097152; off = gid - 1572864u; }
  else                     { src = (const float4*)wo; dst = wob;             off = gid - 1835008u; }
  float4 f = src[off];
  ushort4 o;
  o.x = f2bf(f.x); o.y = f2bf(f.y); o.z = f2bf(f.z); o.w = f2bf(f.w);
  ((ushort4*)dst)[off] = o;
}

// rope tables: cos/sin of l * theta^(-i/32), [2048][32] fp32
__global__ __launch_bounds__(256) void k_rope(float* __restrict__ cosT, float* __restrict__ sinT) {
  int t = blockIdx.x * 256 + threadIdx.x;  // 65536
  int l = t >> 5, i = t & 31;
  float inv = powf(10000.0f, -(float)i * (1.0f / 32.0f));
  float ang = (float)l * inv;
  float s, c;
  sincosf(ang, &s, &c);
  cosT[t] = c;
  sinT[t] = s;
}

// ---------------- shared GEMM main loop (m97 structure) ----------------
__device__ __forceinline__ void gemm_loop(const u16* __restrict__ A, const u16* __restrict__ B,
                                          int m0, int n0, u16* As, u16* Bs, f32x4 acc[4][4]) {
  const int tid = threadIdx.x;
  const int lane = tid & 63, wave = tid >> 6;
  const int quad = lane >> 4, l16 = lane & 15;
  const int wm = wave & 1, wn = wave >> 1;

#pragma unroll
  for (int i = 0; i < 4; ++i)
#pragma unroll
    for (int j = 0; j < 4; ++j)
      acc[i][j] = (f32x4){0.f, 0.f, 0.f, 0.f};

  for (int kt = 0; kt < 16; ++kt) {
    int kb = kt * 64;
#pragma unroll
    for (int it = 0; it < 4; ++it) {
      int idx = it * 256 + tid;       // 0..1023 chunk id
      int row = idx >> 3, c8 = idx & 7;
      gld16(As + idx * 8, A + (long)(m0 + row) * 1024 + kb + c8 * 8);
      gld16(Bs + idx * 8, B + (long)(n0 + row) * 1024 + kb + c8 * 8);
    }
    __syncthreads();
#pragma unroll
    for (int kk = 0; kk < 2; ++kk) {
      bf16x8 a[4], b[4];
#pragma unroll
      for (int i = 0; i < 4; ++i)
        a[i] = ldsv(As + (wm * 64 + i * 16 + l16) * 64 + kk * 32 + quad * 8);
#pragma unroll
      for (int j = 0; j < 4; ++j)
        b[j] = ldsv(Bs + (wn * 64 + j * 16 + l16) * 64 + kk * 32 + quad * 8);
#pragma unroll
      for (int i = 0; i < 4; ++i)
#pragma unroll
        for (int j = 0; j < 4; ++j)
          acc[i][j] = __builtin_amdgcn_mfma_f32_16x16x32_bf16(a[i], b[j], acc[i][j], 0, 0, 0);
    }
    __syncthreads();
  }
}

// ---------------- QKV projection + bias + RoPE + scatter ----------------
__global__ __launch_bounds__(256) void k_qkv(const u16* __restrict__ xb, const u16* __restrict__ wqkvb,
    const float* __restrict__ bq, const float* __restrict__ bk, const float* __restrict__ bv,
    const float* __restrict__ cosT, const float* __restrict__ sinT,
    u16* __restrict__ Qg, u16* __restrict__ Kg, u16* __restrict__ VTg) {
  __shared__ __align__(16) u16 As[128 * 64];
  __shared__ __align__(16) u16 Bs[128 * 64];
  f32x4 acc[4][4];
  int m0 = blockIdx.y * 128, n0 = blockIdx.x * 128;
  gemm_loop(xb, wqkvb, m0, n0, As, Bs, acc);

  const int tid = threadIdx.x, lane = tid & 63, wave = tid >> 6;
  const int quad = lane >> 4, l16 = lane & 15;
  const int wm = wave & 1, wn = wave >> 1;

#pragma unroll
  for (int j = 0; j < 4; ++j) {
    int n = n0 + wn * 64 + j * 16 + l16;   // 0..3071
    int qsel = n >> 10;                    // 0=q 1=k 2=v (uniform across wave)
    int fcol = n & 1023;
    int h = fcol >> 6, d = fcol & 63;
    float bias = (qsel == 0) ? bq[fcol] : (qsel == 1) ? bk[fcol] : bv[fcol];
    int pi = d >> 1;
    float sgn = (d & 1) ? 1.0f : -1.0f;
#pragma unroll
    for (int i = 0; i < 4; ++i) {
#pragma unroll
      for (int r = 0; r < 4; ++r) {
        int m = m0 + wm * 64 + i * 16 + quad * 4 + r;  // token
        int bidx = m >> 11, l = m & 2047;
        float v = acc[i][j][r] + bias;
        float partner = __shfl_xor(v, 1);
        if (qsel == 2) {
          VTg[(((long)bidx * 16 + h) * 64 + d) * 2048 + l] = f2bf(v);
        } else {
          float c = cosT[l * 32 + pi], s = sinT[l * 32 + pi];
          float o = v * c + sgn * partner * s;
          if (qsel == 0) {
            o *= 0.125f;
            Qg[(((long)bidx * 16 + h) * 2048 + l) * 64 + d] = f2bf(o);
          } else {
            Kg[(((long)bidx * 16 + h) * 2048 + l) * 64 + d] = f2bf(o);
          }
        }
      }
    }
  }
}

// ---------------- flash attention, Sᵀ formulation ----------------
// grid (16 q-tiles, 32 bh), 256 thr. Q-tile 128 m-rows. Waves in 2x2:
// wm = m-half (64 rows), wsn = s-half (64 of the 128-s tile).
// S^T = K·Q^T via MFMA -> C-layout has m in columns (l16), s in rows (quad*4+r).
// P (=exp(S-11)) is then directly a legal B-operand for PV using a permuted
// k-order; V^T A-fragments load the same permuted s-order (two b64 reads).
__global__ __launch_bounds__(256, 2) void k_attn(const u16* __restrict__ Qg, const u16* __restrict__ Kg,
    const u16* __restrict__ VTg, u16* __restrict__ Ctx) {
  __shared__ __align__(16) char smem[34816];
  u16* Ks = (u16*)smem;                   // [128][64]
  u16* Vs = (u16*)(smem + 16384);         // [64][132]  (stride 132 breaks bank aliasing)
  const int tid = threadIdx.x, lane = tid & 63, wave = tid >> 6;
  const int quad = lane >> 4, l16 = lane & 15;
  const int wm = wave & 1, wsn = wave >> 1;
  const int bh = blockIdx.y;
  const int m0 = blockIdx.x * 128;
  const u16* Qb = Qg + (long)bh * 2048 * 64;
  const u16* Kb = Kg + (long)bh * 2048 * 64;
  const u16* Vb = VTg + (long)bh * 64 * 2048;

  // Q as B-fragments (rows m = m0 + wm*64 + mt*16 + l16), kept in registers
  bf16x8 qf[4][2];
#pragma unroll
  for (int mt = 0; mt < 4; ++mt)
#pragma unroll
    for (int kk = 0; kk < 2; ++kk)
      qf[mt][kk] = *(const bf16x8*)(Qb + (long)(m0 + wm * 64 + mt * 16 + l16) * 64 + kk * 32 + quad * 8);

  f32x4 oacc[4][4];   // O^T[d-tile][m-tile], C-layout: d = dt*16+quad*4+r, m = mt*16+l16
  float rs[4];        // per-lane partial row sums (row m = mt*16+l16)
#pragma unroll
  for (int dt = 0; dt < 4; ++dt)
#pragma unroll
    for (int mt = 0; mt < 4; ++mt)
      oacc[dt][mt] = (f32x4){0.f, 0.f, 0.f, 0.f};
#pragma unroll
  for (int mt = 0; mt < 4; ++mt) rs[mt] = 0.f;

  for (int st = 0; st < 16; ++st) {
    int s0 = st * 128;
    // stage K [128][64] via global_load_lds
#pragma unroll
    for (int it = 0; it < 4; ++it) {
      int idx = it * 256 + tid;
      int row = idx >> 3, c8 = idx & 7;
      gld16(Ks + idx * 8, Kb + (long)(s0 + row) * 64 + c8 * 8);
    }
    // stage V^T [64][128] -> padded [64][132] via registers
#pragma unroll
    for (int it = 0; it < 4; ++it) {
      int idx = it * 256 + tid;
      int row = idx >> 4, g = idx & 15;
      uint4 vv = *(const uint4*)(Vb + (long)row * 2048 + s0 + g * 8);
      u16* wp = Vs + row * 132 + g * 8;
      *(uint2*)wp = make_uint2(vv.x, vv.y);
      *(uint2*)(wp + 4) = make_uint2(vv.z, vv.w);
    }
    __syncthreads();

    // S^T[s][m] = K·Q^T ; wave computes its 64(s) x 64(m) block
    f32x4 sacc[4][4];
#pragma unroll
    for (int ct = 0; ct < 4; ++ct)
#pragma unroll
      for (int mt = 0; mt < 4; ++mt)
        sacc[ct][mt] = (f32x4){0.f, 0.f, 0.f, 0.f};
#pragma unroll
    for (int kk = 0; kk < 2; ++kk) {
      bf16x8 kf[4];
#pragma unroll
      for (int ct = 0; ct < 4; ++ct)
        kf[ct] = ldsv(Ks + (wsn * 64 + ct * 16 + l16) * 64 + kk * 32 + quad * 8);
#pragma unroll
      for (int ct = 0; ct < 4; ++ct)
#pragma unroll
        for (int mt = 0; mt < 4; ++mt)
          sacc[ct][mt] = __builtin_amdgcn_mfma_f32_16x16x32_bf16(kf[ct], qf[mt][kk], sacc[ct][mt], 0, 0, 0);
    }

    // softmax (fixed shift) + pack + PV, per pair of 16-s tiles (k-chunk c of 32)
#pragma unroll
    for (int c = 0; c < 2; ++c) {
      unsigned pk[2][4][2];
#pragma unroll
      for (int t = 0; t < 2; ++t) {
        int ct = c * 2 + t;
#pragma unroll
        for (int mt = 0; mt < 4; ++mt) {
          unsigned b[4];
          float sum = 0.f;
#pragma unroll
          for (int r = 0; r < 4; ++r) {
            float e = EXP2(fmaf(sacc[ct][mt][r], LOG2E, NFM));
            b[r] = __float_as_uint(e);
            // accumulate the TRUNCATED value so numerator/denominator bias cancels
            sum += __uint_as_float(b[r] & 0xffff0000u);
          }
          rs[mt] += sum;
          pk[t][mt][0] = __builtin_amdgcn_perm(b[1], b[0], 0x07060302u);
          pk[t][mt][1] = __builtin_amdgcn_perm(b[3], b[2], 0x07060302u);
        }
      }
      // O^T += V^T · P  (A = V^T rows d, B = P rows m; k-order permuted consistently:
      // slot (q, j<4) -> s = c*32 + q*4 + j ; slot (q, j>=4) -> s = c*32 + 16 + q*4 + (j-4))
#pragma unroll
      for (int dt = 0; dt < 4; ++dt) {
        const u16* vp = Vs + (dt * 16 + l16) * 132 + wsn * 64 + c * 32 + quad * 4;
        uint2 lo = *(const uint2*)vp;
        uint2 hi = *(const uint2*)(vp + 16);
        U8 vfu; vfu.u = make_uint4(lo.x, lo.y, hi.x, hi.y);
#pragma unroll
        for (int mt = 0; mt < 4; ++mt) {
          U8 pfu; pfu.u = make_uint4(pk[0][mt][0], pk[0][mt][1], pk[1][mt][0], pk[1][mt][1]);
          oacc[dt][mt] = __builtin_amdgcn_mfma_f32_16x16x32_bf16(vfu.v, pfu.v, oacc[dt][mt], 0, 0, 0);
        }
      }
    }
    __syncthreads();
  }

  // merge the two s-half waves via LDS, then finalize + store
  float* mbuf = (float*)smem;
  if (wsn == 1) {
#pragma unroll
    for (int dt = 0; dt < 4; ++dt)
#pragma unroll
      for (int mt = 0; mt < 4; ++mt)
#pragma unroll
        for (int r = 0; r < 4; ++r)
          mbuf[(wm * 68 + dt * 16 + mt * 4 + r) * 64 + lane] = oacc[dt][mt][r];
#pragma unroll
    for (int mt = 0; mt < 4; ++mt)
      mbuf[(wm * 68 + 64 + mt) * 64 + lane] = rs[mt];
  }
  __syncthreads();
  if (wsn == 0) {
#pragma unroll
    for (int dt = 0; dt < 4; ++dt)
#pragma unroll
      for (int mt = 0; mt < 4; ++mt)
#pragma unroll
        for (int r = 0; r < 4; ++r)
          oacc[dt][mt][r] += mbuf[(wm * 68 + dt * 16 + mt * 4 + r) * 64 + lane];
#pragma unroll
    for (int mt = 0; mt < 4; ++mt) {
      rs[mt] += mbuf[(wm * 68 + 64 + mt) * 64 + lane];
      rs[mt] += __shfl_xor(rs[mt], 16);
      rs[mt] += __shfl_xor(rs[mt], 32);
    }
    const int b = bh >> 4, h = bh & 15;
#pragma unroll
    for (int mt = 0; mt < 4; ++mt) {
      float inv = 1.0f / rs[mt];
      int tok = m0 + wm * 64 + mt * 16 + l16;
      u16* cp = Ctx + ((long)(b * 2048 + tok)) * 1024 + h * 64 + quad * 4;
#pragma unroll
      for (int dt = 0; dt < 4; ++dt) {
        float o0 = oacc[dt][mt][0] * inv, o1 = oacc[dt][mt][1] * inv;
        float o2 = oacc[dt][mt][2] * inv, o3 = oacc[dt][mt][3] * inv;
        unsigned u0 = (unsigned)f2bf(o0) | ((unsigned)f2bf(o1) << 16);
        unsigned u1 = (unsigned)f2bf(o2) | ((unsigned)f2bf(o3) << 16);
        *(uint2*)(cp + dt * 16) = make_uint2(u0, u1);
      }
    }
  }
}

// ---------------- output projection ----------------
__global__ __launch_bounds__(256) void k_out(const u16* __restrict__ Ctx, const u16* __restrict__ wob,
    const float* __restrict__ bo, float* __restrict__ out) {
  __shared__ __align__(16) u16 As[128 * 64];
  __shared__ __align__(16) u16 Bs[128 * 64];
  f32x4 acc[4][4];
  int m0 = blockIdx.y * 128, n0 = blockIdx.x * 128;
  gemm_loop(Ctx, wob, m0, n0, As, Bs, acc);
  const int tid = threadIdx.x, lane = tid & 63, wave = tid >> 6;
  const int quad = lane >> 4, l16 = lane & 15;
  const int wm = wave & 1, wn = wave >> 1;
#pragma unroll
  for (int i = 0; i < 4; ++i)
#pragma unroll
    for (int j = 0; j < 4; ++j) {
      int n = n0 + wn * 64 + j * 16 + l16;
      float b_ = bo[n];
#pragma unroll
      for (int r = 0; r < 4; ++r) {
        int m = m0 + wm * 64 + i * 16 + quad * 4 + r;
        out[(long)m * 1024 + n] = acc[i][j][r] + b_;
      }
    }
}

extern "C" void kernel_launch(void* const* d_in, const int* in_sizes, int n_in,
                              void* d_out, int out_size, void* d_ws, size_t ws_size,
                              hipStream_t stream) {
  const float* x  = (const float*)d_in[0];
  const float* Wq = (const float*)d_in[1];
  const float* bq = (const float*)d_in[2];
  const float* Wk = (const float*)d_in[3];
  const float* bk = (const float*)d_in[4];
  const float* Wv = (const float*)d_in[5];
  const float* bv = (const float*)d_in[6];
  const float* Wo = (const float*)d_in[7];
  const float* bo = (const float*)d_in[8];
  float* out = (float*)d_out;

  char* ws = (char*)d_ws;
  u16* xb    = (u16*)(ws);                       // 8 MB  [4096][1024] bf16
  u16* wqkvb = (u16*)(ws + (8ul << 20));         // 6 MB  [3072][1024] bf16
  u16* wob   = (u16*)(ws + (14ul << 20));        // 2 MB  [1024][1024] bf16
  u16* Qg    = (u16*)(ws + (16ul << 20));        // 8 MB  [32][2048][64] bf16 (pre-scaled)
  u16* Kg    = (u16*)(ws + (24ul << 20));        // 8 MB  [32][2048][64] bf16
  u16* VTg   = (u16*)(ws + (32ul << 20));        // 8 MB  [32][64][2048] bf16
  u16* Ctx   = (u16*)(ws + (40ul << 20));        // 8 MB  [4096][1024] bf16
  float* cosT = (float*)(ws + (48ul << 20));     // 256 KB [2048][32]
  float* sinT = (float*)(ws + (48ul << 20) + (256ul << 10));

  k_prep<<<dim3(8192), dim3(256), 0, stream>>>(x, Wq, Wk, Wv, Wo, xb, wqkvb, wob);
  k_rope<<<dim3(256), dim3(256), 0, stream>>>(cosT, sinT);
  k_qkv<<<dim3(24, 32), dim3(256), 0, stream>>>(xb, wqkvb, bq, bk, bv, cosT, sinT, Qg, Kg, VTg);
  k_attn<<<dim3(16, 32), dim3(256), 0, stream>>>(Qg, Kg, VTg, Ctx);
  k_out<<<dim3(8, 32), dim3(256), 0, stream>>>(Ctx, wob, bo, out);
}

// Round 4
// 220.336 us; speedup vs baseline: 1.4389x; 1.1007x over previous
//
#include <hip/hip_runtime.h>

typedef unsigned short u16;
typedef __bf16 bf16x8 __attribute__((ext_vector_type(8)));
typedef float f32x4 __attribute__((ext_vector_type(4)));

#define LOG2E 1.4426950408889634f
#define EXP2(x) __builtin_amdgcn_exp2f(x)
// fixed softmax shift: p = exp(S - 11) == exp2(S*LOG2E - 11*LOG2E)
#define NFM (-11.0f * LOG2E)

__device__ __forceinline__ u16 f2bf(float f) {
  unsigned int u = __float_as_uint(f);
  u += 0x7fffu + ((u >> 16) & 1u);
  return (u16)(u >> 16);
}

// async global->LDS, 16B per lane. LDS dest must be wave-uniform base + lane*16.
__device__ __forceinline__ void gld16(u16* lds, const u16* g) {
  __builtin_amdgcn_global_load_lds((const __attribute__((address_space(1))) unsigned int*)g,
                                   (__attribute__((address_space(3))) unsigned int*)lds,
                                   16, 0, 0);
}

__device__ __forceinline__ bf16x8 ldsv(const u16* p) {
  return *(const bf16x8*)p;
}

union U8 { uint4 u; bf16x8 v; };

// ---------------- prep: fp32 -> bf16 conversions ----------------
__global__ __launch_bounds__(256) void k_prep(const float* __restrict__ x,
    const float* __restrict__ wq, const float* __restrict__ wk,
    const float* __restrict__ wv, const float* __restrict__ wo,
    u16* __restrict__ xb, u16* __restrict__ wqkvb, u16* __restrict__ wob) {
  unsigned gid = blockIdx.x * 256u + threadIdx.x;
  const float4* src;
  u16* dst;
  unsigned off;
  if (gid < 1048576u)      { src = (const float4*)x;  dst = xb;              off = gid; }
  else if (gid < 1310720u) { src = (const float4*)wq; dst = wqkvb;           off = gid - 1048576u; }
  else if (gid < 1572864u) { src = (const float4*)wk; dst = wqkvb + 1048576; off = gid - 1310720u; }
  else if (gid < 1835008u) { src = (const float4*)wv; dst = wqkvb + 2097152; off = gid - 1572864u; }
  else                     { src = (const float4*)wo; dst = wob;             off = gid - 1835008u; }
  float4 f = src[off];
  ushort4 o;
  o.x = f2bf(f.x); o.y = f2bf(f.y); o.z = f2bf(f.z); o.w = f2bf(f.w);
  ((ushort4*)dst)[off] = o;
}

// rope tables: cos/sin of l * theta^(-i/32), [2048][32] fp32
__global__ __launch_bounds__(256) void k_rope(float* __restrict__ cosT, float* __restrict__ sinT) {
  int t = blockIdx.x * 256 + threadIdx.x;  // 65536
  int l = t >> 5, i = t & 31;
  float inv = powf(10000.0f, -(float)i * (1.0f / 32.0f));
  float ang = (float)l * inv;
  float s, c;
  sincosf(ang, &s, &c);
  cosT[t] = c;
  sinT[t] = s;
}

// ---------------- shared GEMM main loop (m97 structure) ----------------
__device__ __forceinline__ void gemm_loop(const u16* __restrict__ A, const u16* __restrict__ B,
                                          int m0, int n0, u16* As, u16* Bs, f32x4 acc[4][4]) {
  const int tid = threadIdx.x;
  const int lane = tid & 63, wave = tid >> 6;
  const int quad = lane >> 4, l16 = lane & 15;
  const int wm = wave & 1, wn = wave >> 1;

#pragma unroll
  for (int i = 0; i < 4; ++i)
#pragma unroll
    for (int j = 0; j < 4; ++j)
      acc[i][j] = (f32x4){0.f, 0.f, 0.f, 0.f};

  for (int kt = 0; kt < 16; ++kt) {
    int kb = kt * 64;
#pragma unroll
    for (int it = 0; it < 4; ++it) {
      int idx = it * 256 + tid;       // 0..1023 chunk id
      int row = idx >> 3, c8 = idx & 7;
      gld16(As + idx * 8, A + (long)(m0 + row) * 1024 + kb + c8 * 8);
      gld16(Bs + idx * 8, B + (long)(n0 + row) * 1024 + kb + c8 * 8);
    }
    __syncthreads();
#pragma unroll
    for (int kk = 0; kk < 2; ++kk) {
      bf16x8 a[4], b[4];
#pragma unroll
      for (int i = 0; i < 4; ++i)
        a[i] = ldsv(As + (wm * 64 + i * 16 + l16) * 64 + kk * 32 + quad * 8);
#pragma unroll
      for (int j = 0; j < 4; ++j)
        b[j] = ldsv(Bs + (wn * 64 + j * 16 + l16) * 64 + kk * 32 + quad * 8);
#pragma unroll
      for (int i = 0; i < 4; ++i)
#pragma unroll
        for (int j = 0; j < 4; ++j)
          acc[i][j] = __builtin_amdgcn_mfma_f32_16x16x32_bf16(a[i], b[j], acc[i][j], 0, 0, 0);
    }
    __syncthreads();
  }
}

// ---------------- QKV projection + bias + RoPE + LDS-bounce coalesced scatter ----
// Blocks x=0..7 -> Q cols, 8..15 -> K cols, 16..23 -> V cols (uniform per block).
__global__ __launch_bounds__(256) void k_qkv(const u16* __restrict__ xb, const u16* __restrict__ wqkvb,
    const float* __restrict__ bq, const float* __restrict__ bk, const float* __restrict__ bv,
    const float* __restrict__ cosT, const float* __restrict__ sinT,
    u16* __restrict__ Qg, u16* __restrict__ Kg, u16* __restrict__ VTg) {
  __shared__ __align__(16) u16 S[128 * 132];   // 33792 B; gemm staging reuses front 32768 B
  u16* As = S;
  u16* Bs = S + 8192;
  f32x4 acc[4][4];
  int m0 = blockIdx.y * 128, n0 = blockIdx.x * 128;
  gemm_loop(xb, wqkvb, m0, n0, As, Bs, acc);

  const int tid = threadIdx.x, lane = tid & 63, wave = tid >> 6;
  const int quad = lane >> 4, l16 = lane & 15;
  const int wm = wave & 1, wn = wave >> 1;
  const int qsel = n0 >> 10;
  const int b = m0 >> 11;
  const int mb0 = m0 & 2047;

  if (qsel < 2) {
    // -------- Q/K: bias + rope in regs, LDS tile [m][n] stride 132, coalesced store
    const float* bp = qsel ? bk : bq;
#pragma unroll
    for (int j = 0; j < 4; ++j) {
      int nl = wn * 64 + j * 16 + l16;
      int n = n0 + nl;
      int fcol = n & 1023;
      int d = fcol & 63;
      int pi = d >> 1;
      float bias = bp[fcol];
      float sgn = (d & 1) ? 1.0f : -1.0f;
#pragma unroll
      for (int i = 0; i < 4; ++i) {
#pragma unroll
        for (int r = 0; r < 4; ++r) {
          int ml = wm * 64 + i * 16 + quad * 4 + r;
          int l = mb0 + ml;
          float v = acc[i][j][r] + bias;
          float partner = __shfl_xor(v, 1);  // value at d^1 (adjacent lane)
          float c = cosT[l * 32 + pi], s = sinT[l * 32 + pi];
          float o = fmaf(v, c, sgn * partner * s);
          if (qsel == 0) o *= 0.125f;        // fold 1/sqrt(HD), exact in bf16
          S[ml * 132 + nl] = f2bf(o);        // banks: 8*quad + l16/2 -> conflict-free
        }
      }
    }
    __syncthreads();
    u16* dstb = (qsel == 0) ? Qg : Kg;
#pragma unroll
    for (int t = 0; t < 16; ++t) {
      int idx = t * 256 + tid;               // 128 m-rows x 32 4-col chunks
      int ml = idx >> 5, c4 = idx & 31;
      int n = n0 + c4 * 4;
      int h = (n & 1023) >> 6;
      int d = n & 63;
      *(uint2*)(dstb + (((long)b * 16 + h) * 2048 + mb0 + ml) * 64 + d) =
          *(const uint2*)(S + ml * 132 + c4 * 4);
    }
  } else {
    // -------- V: bias, LDS tile TRANSPOSED [n][m] stride 132 (r=0..3 pack -> b64 write)
#pragma unroll
    for (int j = 0; j < 4; ++j) {
      int nl = wn * 64 + j * 16 + l16;
      float bias = bv[(n0 + nl) & 1023];
#pragma unroll
      for (int i = 0; i < 4; ++i) {
        int mb = wm * 64 + i * 16 + quad * 4;
        unsigned u0 = (unsigned)f2bf(acc[i][j][0] + bias) | ((unsigned)f2bf(acc[i][j][1] + bias) << 16);
        unsigned u1 = (unsigned)f2bf(acc[i][j][2] + bias) | ((unsigned)f2bf(acc[i][j][3] + bias) << 16);
        *(uint2*)(S + nl * 132 + mb) = make_uint2(u0, u1);
      }
    }
    __syncthreads();
#pragma unroll
    for (int t = 0; t < 16; ++t) {
      int idx = t * 256 + tid;               // 128 d-rows x 32 4-token chunks
      int nl = idx >> 5, c4 = idx & 31;
      int vcol = (n0 & 1023) + nl;
      int h = vcol >> 6, d = vcol & 63;
      *(uint2*)(VTg + (((long)b * 16 + h) * 64 + d) * 2048 + mb0 + c4 * 4) =
          *(const uint2*)(S + nl * 132 + c4 * 4);
    }
  }
}

// ---------------- flash attention, Sᵀ formulation ----------------
// grid (16 q-tiles, 32 bh), 256 thr. Q-tile 128 m-rows. Waves in 2x2:
// wm = m-half (64 rows), wsn = s-half (64 of the 128-s tile).
// S^T = K·Q^T via MFMA -> C-layout has m in columns (l16), s in rows (quad*4+r).
// P (=exp(S-11)) is then directly a legal B-operand for PV using a permuted
// k-order; V^T A-fragments load the same permuted s-order (two b64 reads).
__global__ __launch_bounds__(256, 2) void k_attn(const u16* __restrict__ Qg, const u16* __restrict__ Kg,
    const u16* __restrict__ VTg, u16* __restrict__ Ctx) {
  __shared__ __align__(16) char smem[34816];
  u16* Ks = (u16*)smem;                   // [128][64]
  u16* Vs = (u16*)(smem + 16384);         // [64][132]  (stride 132 breaks bank aliasing)
  const int tid = threadIdx.x, lane = tid & 63, wave = tid >> 6;
  const int quad = lane >> 4, l16 = lane & 15;
  const int wm = wave & 1, wsn = wave >> 1;
  const int bh = blockIdx.y;
  const int m0 = blockIdx.x * 128;
  const u16* Qb = Qg + (long)bh * 2048 * 64;
  const u16* Kb = Kg + (long)bh * 2048 * 64;
  const u16* Vb = VTg + (long)bh * 64 * 2048;

  // Q as B-fragments (rows m = m0 + wm*64 + mt*16 + l16), kept in registers
  bf16x8 qf[4][2];
#pragma unroll
  for (int mt = 0; mt < 4; ++mt)
#pragma unroll
    for (int kk = 0; kk < 2; ++kk)
      qf[mt][kk] = *(const bf16x8*)(Qb + (long)(m0 + wm * 64 + mt * 16 + l16) * 64 + kk * 32 + quad * 8);

  f32x4 oacc[4][4];   // O^T[d-tile][m-tile], C-layout: d = dt*16+quad*4+r, m = mt*16+l16
  float rs[4];        // per-lane partial row sums (row m = mt*16+l16)
#pragma unroll
  for (int dt = 0; dt < 4; ++dt)
#pragma unroll
    for (int mt = 0; mt < 4; ++mt)
      oacc[dt][mt] = (f32x4){0.f, 0.f, 0.f, 0.f};
#pragma unroll
  for (int mt = 0; mt < 4; ++mt) rs[mt] = 0.f;

  for (int st = 0; st < 16; ++st) {
    int s0 = st * 128;
    // stage K [128][64] via global_load_lds
#pragma unroll
    for (int it = 0; it < 4; ++it) {
      int idx = it * 256 + tid;
      int row = idx >> 3, c8 = idx & 7;
      gld16(Ks + idx * 8, Kb + (long)(s0 + row) * 64 + c8 * 8);
    }
    // stage V^T [64][128] -> padded [64][132] via registers
#pragma unroll
    for (int it = 0; it < 4; ++it) {
      int idx = it * 256 + tid;
      int row = idx >> 4, g = idx & 15;
      uint4 vv = *(const uint4*)(Vb + (long)row * 2048 + s0 + g * 8);
      u16* wp = Vs + row * 132 + g * 8;
      *(uint2*)wp = make_uint2(vv.x, vv.y);
      *(uint2*)(wp + 4) = make_uint2(vv.z, vv.w);
    }
    __syncthreads();

    // S^T[s][m] = K·Q^T ; wave computes its 64(s) x 64(m) block
    f32x4 sacc[4][4];
#pragma unroll
    for (int ct = 0; ct < 4; ++ct)
#pragma unroll
      for (int mt = 0; mt < 4; ++mt)
        sacc[ct][mt] = (f32x4){0.f, 0.f, 0.f, 0.f};
#pragma unroll
    for (int kk = 0; kk < 2; ++kk) {
      bf16x8 kf[4];
#pragma unroll
      for (int ct = 0; ct < 4; ++ct)
        kf[ct] = ldsv(Ks + (wsn * 64 + ct * 16 + l16) * 64 + kk * 32 + quad * 8);
#pragma unroll
      for (int ct = 0; ct < 4; ++ct)
#pragma unroll
        for (int mt = 0; mt < 4; ++mt)
          sacc[ct][mt] = __builtin_amdgcn_mfma_f32_16x16x32_bf16(kf[ct], qf[mt][kk], sacc[ct][mt], 0, 0, 0);
    }

    // softmax (fixed shift) + pack + PV, per pair of 16-s tiles (k-chunk c of 32)
#pragma unroll
    for (int c = 0; c < 2; ++c) {
      unsigned pk[2][4][2];
#pragma unroll
      for (int t = 0; t < 2; ++t) {
        int ct = c * 2 + t;
#pragma unroll
        for (int mt = 0; mt < 4; ++mt) {
          unsigned b[4];
          float sum = 0.f;
#pragma unroll
          for (int r = 0; r < 4; ++r) {
            float e = EXP2(fmaf(sacc[ct][mt][r], LOG2E, NFM));
            b[r] = __float_as_uint(e);
            // accumulate the TRUNCATED value so numerator/denominator bias cancels
            sum += __uint_as_float(b[r] & 0xffff0000u);
          }
          rs[mt] += sum;
          pk[t][mt][0] = __builtin_amdgcn_perm(b[1], b[0], 0x07060302u);
          pk[t][mt][1] = __builtin_amdgcn_perm(b[3], b[2], 0x07060302u);
        }
      }
      // O^T += V^T · P  (A = V^T rows d, B = P rows m; k-order permuted consistently)
#pragma unroll
      for (int dt = 0; dt < 4; ++dt) {
        const u16* vp = Vs + (dt * 16 + l16) * 132 + wsn * 64 + c * 32 + quad * 4;
        uint2 lo = *(const uint2*)vp;
        uint2 hi = *(const uint2*)(vp + 16);
        U8 vfu; vfu.u = make_uint4(lo.x, lo.y, hi.x, hi.y);
#pragma unroll
        for (int mt = 0; mt < 4; ++mt) {
          U8 pfu; pfu.u = make_uint4(pk[0][mt][0], pk[0][mt][1], pk[1][mt][0], pk[1][mt][1]);
          oacc[dt][mt] = __builtin_amdgcn_mfma_f32_16x16x32_bf16(vfu.v, pfu.v, oacc[dt][mt], 0, 0, 0);
        }
      }
    }
    __syncthreads();
  }

  // merge the two s-half waves via LDS, then finalize + store
  float* mbuf = (float*)smem;
  if (wsn == 1) {
#pragma unroll
    for (int dt = 0; dt < 4; ++dt)
#pragma unroll
      for (int mt = 0; mt < 4; ++mt)
#pragma unroll
        for (int r = 0; r < 4; ++r)
          mbuf[(wm * 68 + dt * 16 + mt * 4 + r) * 64 + lane] = oacc[dt][mt][r];
#pragma unroll
    for (int mt = 0; mt < 4; ++mt)
      mbuf[(wm * 68 + 64 + mt) * 64 + lane] = rs[mt];
  }
  __syncthreads();
  if (wsn == 0) {
#pragma unroll
    for (int dt = 0; dt < 4; ++dt)
#pragma unroll
      for (int mt = 0; mt < 4; ++mt)
#pragma unroll
        for (int r = 0; r < 4; ++r)
          oacc[dt][mt][r] += mbuf[(wm * 68 + dt * 16 + mt * 4 + r) * 64 + lane];
#pragma unroll
    for (int mt = 0; mt < 4; ++mt) {
      rs[mt] += mbuf[(wm * 68 + 64 + mt) * 64 + lane];
      rs[mt] += __shfl_xor(rs[mt], 16);
      rs[mt] += __shfl_xor(rs[mt], 32);
    }
    const int b = bh >> 4, h = bh & 15;
#pragma unroll
    for (int mt = 0; mt < 4; ++mt) {
      float inv = 1.0f / rs[mt];
      int tok = m0 + wm * 64 + mt * 16 + l16;
      u16* cp = Ctx + ((long)(b * 2048 + tok)) * 1024 + h * 64 + quad * 4;
#pragma unroll
      for (int dt = 0; dt < 4; ++dt) {
        float o0 = oacc[dt][mt][0] * inv, o1 = oacc[dt][mt][1] * inv;
        float o2 = oacc[dt][mt][2] * inv, o3 = oacc[dt][mt][3] * inv;
        unsigned u0 = (unsigned)f2bf(o0) | ((unsigned)f2bf(o1) << 16);
        unsigned u1 = (unsigned)f2bf(o2) | ((unsigned)f2bf(o3) << 16);
        *(uint2*)(cp + dt * 16) = make_uint2(u0, u1);
      }
    }
  }
}

// ---------------- output projection ----------------
__global__ __launch_bounds__(256) void k_out(const u16* __restrict__ Ctx, const u16* __restrict__ wob,
    const float* __restrict__ bo, float* __restrict__ out) {
  __shared__ __align__(16) u16 As[128 * 64];
  __shared__ __align__(16) u16 Bs[128 * 64];
  f32x4 acc[4][4];
  int m0 = blockIdx.y * 128, n0 = blockIdx.x * 128;
  gemm_loop(Ctx, wob, m0, n0, As, Bs, acc);
  const int tid = threadIdx.x, lane = tid & 63, wave = tid >> 6;
  const int quad = lane >> 4, l16 = lane & 15;
  const int wm = wave & 1, wn = wave >> 1;
#pragma unroll
  for (int i = 0; i < 4; ++i)
#pragma unroll
    for (int j = 0; j < 4; ++j) {
      int n = n0 + wn * 64 + j * 16 + l16;
      float b_ = bo[n];
#pragma unroll
      for (int r = 0; r < 4; ++r) {
        int m = m0 + wm * 64 + i * 16 + quad * 4 + r;
        out[(long)m * 1024 + n] = acc[i][j][r] + b_;
      }
    }
}

extern "C" void kernel_launch(void* const* d_in, const int* in_sizes, int n_in,
                              void* d_out, int out_size, void* d_ws, size_t ws_size,
                              hipStream_t stream) {
  const float* x  = (const float*)d_in[0];
  const float* Wq = (const float*)d_in[1];
  const float* bq = (const float*)d_in[2];
  const float* Wk = (const float*)d_in[3];
  const float* bk = (const float*)d_in[4];
  const float* Wv = (const float*)d_in[5];
  const float* bv = (const float*)d_in[6];
  const float* Wo = (const float*)d_in[7];
  const float* bo = (const float*)d_in[8];
  float* out = (float*)d_out;

  char* ws = (char*)d_ws;
  u16* xb    = (u16*)(ws);                       // 8 MB  [4096][1024] bf16
  u16* wqkvb = (u16*)(ws + (8ul << 20));         // 6 MB  [3072][1024] bf16
  u16* wob   = (u16*)(ws + (14ul << 20));        // 2 MB  [1024][1024] bf16
  u16* Qg    = (u16*)(ws + (16ul << 20));        // 8 MB  [32][2048][64] bf16 (pre-scaled)
  u16* Kg    = (u16*)(ws + (24ul << 20));        // 8 MB  [32][2048][64] bf16
  u16* VTg   = (u16*)(ws + (32ul << 20));        // 8 MB  [32][64][2048] bf16
  u16* Ctx   = (u16*)(ws + (40ul << 20));        // 8 MB  [4096][1024] bf16
  float* cosT = (float*)(ws + (48ul << 20));     // 256 KB [2048][32]
  float* sinT = (float*)(ws + (48ul << 20) + (256ul << 10));

  k_prep<<<dim3(8192), dim3(256), 0, stream>>>(x, Wq, Wk, Wv, Wo, xb, wqkvb, wob);
  k_rope<<<dim3(256), dim3(256), 0, stream>>>(cosT, sinT);
  k_qkv<<<dim3(24, 32), dim3(256), 0, stream>>>(xb, wqkvb, bq, bk, bv, cosT, sinT, Qg, Kg, VTg);
  k_attn<<<dim3(16, 32), dim3(256), 0, stream>>>(Qg, Kg, VTg, Ctx);
  k_out<<<dim3(8, 32), dim3(256), 0, stream>>>(Ctx, wob, bo, out);
}

// Round 5
// 212.364 us; speedup vs baseline: 1.4929x; 1.0375x over previous
//
#include <hip/hip_runtime.h>

typedef unsigned short u16;
typedef __bf16 bf16x8 __attribute__((ext_vector_type(8)));
typedef float f32x4 __attribute__((ext_vector_type(4)));

#define LOG2E 1.4426950408889634f
#define EXP2(x) __builtin_amdgcn_exp2f(x)
// fixed softmax shift: p = exp(S - 11) == exp2(S*LOG2E - 11*LOG2E)
#define NFM (-11.0f * LOG2E)

__device__ __forceinline__ u16 f2bf(float f) {
  unsigned int u = __float_as_uint(f);
  u += 0x7fffu + ((u >> 16) & 1u);
  return (u16)(u >> 16);
}

// async global->LDS, 16B per lane. LDS dest must be wave-uniform base + lane*16.
__device__ __forceinline__ void gld16(u16* lds, const u16* g) {
  __builtin_amdgcn_global_load_lds((const __attribute__((address_space(1))) unsigned int*)g,
                                   (__attribute__((address_space(3))) unsigned int*)lds,
                                   16, 0, 0);
}

__device__ __forceinline__ bf16x8 ldsv(const u16* p) {
  return *(const bf16x8*)p;
}

union U8 { uint4 u; bf16x8 v; };

// ---------------- prep: fp32 -> bf16 conversions ----------------
__global__ __launch_bounds__(256) void k_prep(const float* __restrict__ x,
    const float* __restrict__ wq, const float* __restrict__ wk,
    const float* __restrict__ wv, const float* __restrict__ wo,
    u16* __restrict__ xb, u16* __restrict__ wqkvb, u16* __restrict__ wob) {
  unsigned gid = blockIdx.x * 256u + threadIdx.x;
  const float4* src;
  u16* dst;
  unsigned off;
  if (gid < 1048576u)      { src = (const float4*)x;  dst = xb;              off = gid; }
  else if (gid < 1310720u) { src = (const float4*)wq; dst = wqkvb;           off = gid - 1048576u; }
  else if (gid < 1572864u) { src = (const float4*)wk; dst = wqkvb + 1048576; off = gid - 1310720u; }
  else if (gid < 1835008u) { src = (const float4*)wv; dst = wqkvb + 2097152; off = gid - 1572864u; }
  else                     { src = (const float4*)wo; dst = wob;             off = gid - 1835008u; }
  float4 f = src[off];
  ushort4 o;
  o.x = f2bf(f.x); o.y = f2bf(f.y); o.z = f2bf(f.z); o.w = f2bf(f.w);
  ((ushort4*)dst)[off] = o;
}

// rope tables: cos/sin of l * theta^(-i/32), [2048][32] fp32
__global__ __launch_bounds__(256) void k_rope(float* __restrict__ cosT, float* __restrict__ sinT) {
  int t = blockIdx.x * 256 + threadIdx.x;  // 65536
  int l = t >> 5, i = t & 31;
  float inv = powf(10000.0f, -(float)i * (1.0f / 32.0f));
  float ang = (float)l * inv;
  float s, c;
  sincosf(ang, &s, &c);
  cosT[t] = c;
  sinT[t] = s;
}

// ---------------- shared GEMM main loop (m97 structure + XOR bank swizzle) -------
// LDS slot (row, c8) holds global chunk c8^(row&7); fragment read for chunk c at
// row r uses slot c^(r&7). r&7 == l16&7 spreads the 16 fragment lanes over all
// 32 banks (was: 16 lanes on 4 banks -> 2x LDS-read cost).
__device__ __forceinline__ void gemm_loop(const u16* __restrict__ A, const u16* __restrict__ B,
                                          int m0, int n0, u16* As, u16* Bs, f32x4 acc[4][4]) {
  const int tid = threadIdx.x;
  const int lane = tid & 63, wave = tid >> 6;
  const int quad = lane >> 4, l16 = lane & 15;
  const int wm = wave & 1, wn = wave >> 1;
  const int sw = l16 & 7;

#pragma unroll
  for (int i = 0; i < 4; ++i)
#pragma unroll
    for (int j = 0; j < 4; ++j)
      acc[i][j] = (f32x4){0.f, 0.f, 0.f, 0.f};

  for (int kt = 0; kt < 16; ++kt) {
    int kb = kt * 64;
#pragma unroll
    for (int it = 0; it < 4; ++it) {
      int idx = it * 256 + tid;       // 0..1023 chunk id
      int row = idx >> 3, c8 = idx & 7;
      int sc = c8 ^ (row & 7);
      gld16(As + idx * 8, A + (long)(m0 + row) * 1024 + kb + sc * 8);
      gld16(Bs + idx * 8, B + (long)(n0 + row) * 1024 + kb + sc * 8);
    }
    __syncthreads();
#pragma unroll
    for (int kk = 0; kk < 2; ++kk) {
      int ch = (kk * 4 + quad) ^ sw;
      bf16x8 a[4], b[4];
#pragma unroll
      for (int i = 0; i < 4; ++i)
        a[i] = ldsv(As + (wm * 64 + i * 16 + l16) * 64 + ch * 8);
#pragma unroll
      for (int j = 0; j < 4; ++j)
        b[j] = ldsv(Bs + (wn * 64 + j * 16 + l16) * 64 + ch * 8);
#pragma unroll
      for (int i = 0; i < 4; ++i)
#pragma unroll
        for (int j = 0; j < 4; ++j)
          acc[i][j] = __builtin_amdgcn_mfma_f32_16x16x32_bf16(a[i], b[j], acc[i][j], 0, 0, 0);
    }
    __syncthreads();
  }
}

// ---------------- QKV projection + bias + RoPE + LDS-bounce coalesced scatter ----
// Blocks x=0..7 -> Q cols, 8..15 -> K cols, 16..23 -> V cols (uniform per block).
__global__ __launch_bounds__(256) void k_qkv(const u16* __restrict__ xb, const u16* __restrict__ wqkvb,
    const float* __restrict__ bq, const float* __restrict__ bk, const float* __restrict__ bv,
    const float* __restrict__ cosT, const float* __restrict__ sinT,
    u16* __restrict__ Qg, u16* __restrict__ Kg, u16* __restrict__ VTg) {
  __shared__ __align__(16) u16 S[128 * 132];   // 33792 B; gemm staging reuses front 32768 B
  u16* As = S;
  u16* Bs = S + 8192;
  f32x4 acc[4][4];
  int m0 = blockIdx.y * 128, n0 = blockIdx.x * 128;
  gemm_loop(xb, wqkvb, m0, n0, As, Bs, acc);

  const int tid = threadIdx.x, lane = tid & 63, wave = tid >> 6;
  const int quad = lane >> 4, l16 = lane & 15;
  const int wm = wave & 1, wn = wave >> 1;
  const int qsel = n0 >> 10;
  const int b = m0 >> 11;
  const int mb0 = m0 & 2047;

  if (qsel < 2) {
    // -------- Q/K: bias + rope in regs, LDS tile [m][n] stride 132, coalesced store
    const float* bp = qsel ? bk : bq;
#pragma unroll
    for (int j = 0; j < 4; ++j) {
      int nl = wn * 64 + j * 16 + l16;
      int n = n0 + nl;
      int fcol = n & 1023;
      int d = fcol & 63;
      int pi = d >> 1;
      float bias = bp[fcol];
      float sgn = (d & 1) ? 1.0f : -1.0f;
#pragma unroll
      for (int i = 0; i < 4; ++i) {
#pragma unroll
        for (int r = 0; r < 4; ++r) {
          int ml = wm * 64 + i * 16 + quad * 4 + r;
          int l = mb0 + ml;
          float v = acc[i][j][r] + bias;
          float partner = __shfl_xor(v, 1);  // value at d^1 (adjacent lane)
          float c = cosT[l * 32 + pi], s = sinT[l * 32 + pi];
          float o = fmaf(v, c, sgn * partner * s);
          if (qsel == 0) o *= 0.125f;        // fold 1/sqrt(HD), exact in bf16
          S[ml * 132 + nl] = f2bf(o);        // banks: 8*quad + l16/2 -> conflict-free
        }
      }
    }
    __syncthreads();
    u16* dstb = (qsel == 0) ? Qg : Kg;
#pragma unroll
    for (int t = 0; t < 16; ++t) {
      int idx = t * 256 + tid;               // 128 m-rows x 32 4-col chunks
      int ml = idx >> 5, c4 = idx & 31;
      int n = n0 + c4 * 4;
      int h = (n & 1023) >> 6;
      int d = n & 63;
      *(uint2*)(dstb + (((long)b * 16 + h) * 2048 + mb0 + ml) * 64 + d) =
          *(const uint2*)(S + ml * 132 + c4 * 4);
    }
  } else {
    // -------- V: bias, LDS tile TRANSPOSED [n][m] stride 132 (r=0..3 pack -> b64 write)
#pragma unroll
    for (int j = 0; j < 4; ++j) {
      int nl = wn * 64 + j * 16 + l16;
      float bias = bv[(n0 + nl) & 1023];
#pragma unroll
      for (int i = 0; i < 4; ++i) {
        int mb = wm * 64 + i * 16 + quad * 4;
        unsigned u0 = (unsigned)f2bf(acc[i][j][0] + bias) | ((unsigned)f2bf(acc[i][j][1] + bias) << 16);
        unsigned u1 = (unsigned)f2bf(acc[i][j][2] + bias) | ((unsigned)f2bf(acc[i][j][3] + bias) << 16);
        *(uint2*)(S + nl * 132 + mb) = make_uint2(u0, u1);
      }
    }
    __syncthreads();
#pragma unroll
    for (int t = 0; t < 16; ++t) {
      int idx = t * 256 + tid;               // 128 d-rows x 32 4-token chunks
      int nl = idx >> 5, c4 = idx & 31;
      int vcol = (n0 & 1023) + nl;
      int h = vcol >> 6, d = vcol & 63;
      *(uint2*)(VTg + (((long)b * 16 + h) * 64 + d) * 2048 + mb0 + c4 * 4) =
          *(const uint2*)(S + nl * 132 + c4 * 4);
    }
  }
}

// ---------------- flash attention, Sᵀ formulation ----------------
// grid (16 q-tiles, 32 bh), 256 thr. Q-tile 128 m-rows. Waves in 2x2:
// wm = m-half (64 rows), wsn = s-half (64 of the 128-s tile).
// S^T = K·Q^T via MFMA -> C-layout has m in columns (l16), s in rows (quad*4+r).
// P (=exp(S-11)) is then directly a legal B-operand for PV using a permuted
// k-order; V^T A-fragments load the same permuted s-order (two b64 reads).
// Ks uses the same XOR bank swizzle as gemm_loop.
__global__ __launch_bounds__(256, 2) void k_attn(const u16* __restrict__ Qg, const u16* __restrict__ Kg,
    const u16* __restrict__ VTg, u16* __restrict__ Ctx) {
  __shared__ __align__(16) char smem[34816];
  u16* Ks = (u16*)smem;                   // [128][64], chunk-swizzled
  u16* Vs = (u16*)(smem + 16384);         // [64][132]  (stride 132 breaks bank aliasing)
  const int tid = threadIdx.x, lane = tid & 63, wave = tid >> 6;
  const int quad = lane >> 4, l16 = lane & 15;
  const int wm = wave & 1, wsn = wave >> 1;
  const int sw = l16 & 7;
  const int bh = blockIdx.y;
  const int m0 = blockIdx.x * 128;
  const u16* Qb = Qg + (long)bh * 2048 * 64;
  const u16* Kb = Kg + (long)bh * 2048 * 64;
  const u16* Vb = VTg + (long)bh * 64 * 2048;

  // Q as B-fragments (rows m = m0 + wm*64 + mt*16 + l16), kept in registers
  bf16x8 qf[4][2];
#pragma unroll
  for (int mt = 0; mt < 4; ++mt)
#pragma unroll
    for (int kk = 0; kk < 2; ++kk)
      qf[mt][kk] = *(const bf16x8*)(Qb + (long)(m0 + wm * 64 + mt * 16 + l16) * 64 + kk * 32 + quad * 8);

  f32x4 oacc[4][4];   // O^T[d-tile][m-tile], C-layout: d = dt*16+quad*4+r, m = mt*16+l16
  float rs[4];        // per-lane partial row sums (row m = mt*16+l16)
#pragma unroll
  for (int dt = 0; dt < 4; ++dt)
#pragma unroll
    for (int mt = 0; mt < 4; ++mt)
      oacc[dt][mt] = (f32x4){0.f, 0.f, 0.f, 0.f};
#pragma unroll
  for (int mt = 0; mt < 4; ++mt) rs[mt] = 0.f;

  for (int st = 0; st < 16; ++st) {
    int s0 = st * 128;
    // stage K [128][64] via global_load_lds, chunk-swizzled
#pragma unroll
    for (int it = 0; it < 4; ++it) {
      int idx = it * 256 + tid;
      int row = idx >> 3, c8 = idx & 7;
      int sc = c8 ^ (row & 7);
      gld16(Ks + idx * 8, Kb + (long)(s0 + row) * 64 + sc * 8);
    }
    // stage V^T [64][128] -> padded [64][132] via registers
#pragma unroll
    for (int it = 0; it < 4; ++it) {
      int idx = it * 256 + tid;
      int row = idx >> 4, g = idx & 15;
      uint4 vv = *(const uint4*)(Vb + (long)row * 2048 + s0 + g * 8);
      u16* wp = Vs + row * 132 + g * 8;
      *(uint2*)wp = make_uint2(vv.x, vv.y);
      *(uint2*)(wp + 4) = make_uint2(vv.z, vv.w);
    }
    __syncthreads();

    // S^T[s][m] = K·Q^T ; wave computes its 64(s) x 64(m) block
    f32x4 sacc[4][4];
#pragma unroll
    for (int ct = 0; ct < 4; ++ct)
#pragma unroll
      for (int mt = 0; mt < 4; ++mt)
        sacc[ct][mt] = (f32x4){0.f, 0.f, 0.f, 0.f};
#pragma unroll
    for (int kk = 0; kk < 2; ++kk) {
      int ch = (kk * 4 + quad) ^ sw;
      bf16x8 kf[4];
#pragma unroll
      for (int ct = 0; ct < 4; ++ct)
        kf[ct] = ldsv(Ks + (wsn * 64 + ct * 16 + l16) * 64 + ch * 8);
#pragma unroll
      for (int ct = 0; ct < 4; ++ct)
#pragma unroll
        for (int mt = 0; mt < 4; ++mt)
          sacc[ct][mt] = __builtin_amdgcn_mfma_f32_16x16x32_bf16(kf[ct], qf[mt][kk], sacc[ct][mt], 0, 0, 0);
    }

    // softmax (fixed shift) + pack + PV, per pair of 16-s tiles (k-chunk c of 32)
#pragma unroll
    for (int c = 0; c < 2; ++c) {
      unsigned pk[2][4][2];
#pragma unroll
      for (int t = 0; t < 2; ++t) {
        int ct = c * 2 + t;
#pragma unroll
        for (int mt = 0; mt < 4; ++mt) {
          unsigned b[4];
          float sum = 0.f;
#pragma unroll
          for (int r = 0; r < 4; ++r) {
            float e = EXP2(fmaf(sacc[ct][mt][r], LOG2E, NFM));
            b[r] = __float_as_uint(e);
            // accumulate the TRUNCATED value so numerator/denominator bias cancels
            sum += __uint_as_float(b[r] & 0xffff0000u);
          }
          rs[mt] += sum;
          pk[t][mt][0] = __builtin_amdgcn_perm(b[1], b[0], 0x07060302u);
          pk[t][mt][1] = __builtin_amdgcn_perm(b[3], b[2], 0x07060302u);
        }
      }
      // O^T += V^T · P  (A = V^T rows d, B = P rows m; k-order permuted consistently)
#pragma unroll
      for (int dt = 0; dt < 4; ++dt) {
        const u16* vp = Vs + (dt * 16 + l16) * 132 + wsn * 64 + c * 32 + quad * 4;
        uint2 lo = *(const uint2*)vp;
        uint2 hi = *(const uint2*)(vp + 16);
        U8 vfu; vfu.u = make_uint4(lo.x, lo.y, hi.x, hi.y);
#pragma unroll
        for (int mt = 0; mt < 4; ++mt) {
          U8 pfu; pfu.u = make_uint4(pk[0][mt][0], pk[0][mt][1], pk[1][mt][0], pk[1][mt][1]);
          oacc[dt][mt] = __builtin_amdgcn_mfma_f32_16x16x32_bf16(vfu.v, pfu.v, oacc[dt][mt], 0, 0, 0);
        }
      }
    }
    __syncthreads();
  }

  // merge the two s-half waves via LDS, then finalize + store
  float* mbuf = (float*)smem;
  if (wsn == 1) {
#pragma unroll
    for (int dt = 0; dt < 4; ++dt)
#pragma unroll
      for (int mt = 0; mt < 4; ++mt)
#pragma unroll
        for (int r = 0; r < 4; ++r)
          mbuf[(wm * 68 + dt * 16 + mt * 4 + r) * 64 + lane] = oacc[dt][mt][r];
#pragma unroll
    for (int mt = 0; mt < 4; ++mt)
      mbuf[(wm * 68 + 64 + mt) * 64 + lane] = rs[mt];
  }
  __syncthreads();
  if (wsn == 0) {
#pragma unroll
    for (int dt = 0; dt < 4; ++dt)
#pragma unroll
      for (int mt = 0; mt < 4; ++mt)
#pragma unroll
        for (int r = 0; r < 4; ++r)
          oacc[dt][mt][r] += mbuf[(wm * 68 + dt * 16 + mt * 4 + r) * 64 + lane];
#pragma unroll
    for (int mt = 0; mt < 4; ++mt) {
      rs[mt] += mbuf[(wm * 68 + 64 + mt) * 64 + lane];
      rs[mt] += __shfl_xor(rs[mt], 16);
      rs[mt] += __shfl_xor(rs[mt], 32);
    }
    const int b = bh >> 4, h = bh & 15;
#pragma unroll
    for (int mt = 0; mt < 4; ++mt) {
      float inv = 1.0f / rs[mt];
      int tok = m0 + wm * 64 + mt * 16 + l16;
      u16* cp = Ctx + ((long)(b * 2048 + tok)) * 1024 + h * 64 + quad * 4;
#pragma unroll
      for (int dt = 0; dt < 4; ++dt) {
        float o0 = oacc[dt][mt][0] * inv, o1 = oacc[dt][mt][1] * inv;
        float o2 = oacc[dt][mt][2] * inv, o3 = oacc[dt][mt][3] * inv;
        unsigned u0 = (unsigned)f2bf(o0) | ((unsigned)f2bf(o1) << 16);
        unsigned u1 = (unsigned)f2bf(o2) | ((unsigned)f2bf(o3) << 16);
        *(uint2*)(cp + dt * 16) = make_uint2(u0, u1);
      }
    }
  }
}

// ---------------- output projection ----------------
__global__ __launch_bounds__(256) void k_out(const u16* __restrict__ Ctx, const u16* __restrict__ wob,
    const float* __restrict__ bo, float* __restrict__ out) {
  __shared__ __align__(16) u16 As[128 * 64];
  __shared__ __align__(16) u16 Bs[128 * 64];
  f32x4 acc[4][4];
  int m0 = blockIdx.y * 128, n0 = blockIdx.x * 128;
  gemm_loop(Ctx, wob, m0, n0, As, Bs, acc);
  const int tid = threadIdx.x, lane = tid & 63, wave = tid >> 6;
  const int quad = lane >> 4, l16 = lane & 15;
  const int wm = wave & 1, wn = wave >> 1;
#pragma unroll
  for (int i = 0; i < 4; ++i)
#pragma unroll
    for (int j = 0; j < 4; ++j) {
      int n = n0 + wn * 64 + j * 16 + l16;
      float b_ = bo[n];
#pragma unroll
      for (int r = 0; r < 4; ++r) {
        int m = m0 + wm * 64 + i * 16 + quad * 4 + r;
        out[(long)m * 1024 + n] = acc[i][j][r] + b_;
      }
    }
}

extern "C" void kernel_launch(void* const* d_in, const int* in_sizes, int n_in,
                              void* d_out, int out_size, void* d_ws, size_t ws_size,
                              hipStream_t stream) {
  const float* x  = (const float*)d_in[0];
  const float* Wq = (const float*)d_in[1];
  const float* bq = (const float*)d_in[2];
  const float* Wk = (const float*)d_in[3];
  const float* bk = (const float*)d_in[4];
  const float* Wv = (const float*)d_in[5];
  const float* bv = (const float*)d_in[6];
  const float* Wo = (const float*)d_in[7];
  const float* bo = (const float*)d_in[8];
  float* out = (float*)d_out;

  char* ws = (char*)d_ws;
  u16* xb    = (u16*)(ws);                       // 8 MB  [4096][1024] bf16
  u16* wqkvb = (u16*)(ws + (8ul << 20));         // 6 MB  [3072][1024] bf16
  u16* wob   = (u16*)(ws + (14ul << 20));        // 2 MB  [1024][1024] bf16
  u16* Qg    = (u16*)(ws + (16ul << 20));        // 8 MB  [32][2048][64] bf16 (pre-scaled)
  u16* Kg    = (u16*)(ws + (24ul << 20));        // 8 MB  [32][2048][64] bf16
  u16* VTg   = (u16*)(ws + (32ul << 20));        // 8 MB  [32][64][2048] bf16
  u16* Ctx   = (u16*)(ws + (40ul << 20));        // 8 MB  [4096][1024] bf16
  float* cosT = (float*)(ws + (48ul << 20));     // 256 KB [2048][32]
  float* sinT = (float*)(ws + (48ul << 20) + (256ul << 10));

  k_prep<<<dim3(8192), dim3(256), 0, stream>>>(x, Wq, Wk, Wv, Wo, xb, wqkvb, wob);
  k_rope<<<dim3(256), dim3(256), 0, stream>>>(cosT, sinT);
  k_qkv<<<dim3(24, 32), dim3(256), 0, stream>>>(xb, wqkvb, bq, bk, bv, cosT, sinT, Qg, Kg, VTg);
  k_attn<<<dim3(16, 32), dim3(256), 0, stream>>>(Qg, Kg, VTg, Ctx);
  k_out<<<dim3(8, 32), dim3(256), 0, stream>>>(Ctx, wob, bo, out);
}